// Round 7
// baseline (358.460 us; speedup 1.0000x reference)
//
#include <hip/hip_runtime.h>
#include <math.h>

#define PLANES   8192   // 16 batches * 512 channels
#define PLANE_SZ 4096   // 64*64
#define CHANS    512
#define NBLK     1024   // 4 blocks/CU * 256 CUs -> co-resident (launch_bounds)
#define PPB      4      // planes per block per phase
#define NPHASE   2      // 1024*4*2 = 8192 planes; phase = 8 whole batches
#define NGRP     16
#define GRP_SZ   (NBLK / NGRP)

typedef float f32x4 __attribute__((ext_vector_type(4)));

// ---------------------------------------------------------------------------
// Two-level generation barrier (regular launch, graph-capture safe).
// State zeroed by hipMemsetAsync at the start of every kernel_launch.
// Proven correct in R5/R6.
// ---------------------------------------------------------------------------
__device__ __forceinline__ void grid_barrier(unsigned* cnt, unsigned* root,
                                             unsigned* gen, int gid)
{
    __syncthreads();
    if (threadIdx.x == 0) {
        unsigned g = __hip_atomic_load(gen, __ATOMIC_RELAXED, __HIP_MEMORY_SCOPE_AGENT);
        __threadfence();   // release gp writes to device scope
        unsigned a = __hip_atomic_fetch_add(&cnt[gid * 16], 1u,
                                            __ATOMIC_ACQ_REL, __HIP_MEMORY_SCOPE_AGENT);
        if (a == GRP_SZ - 1) {
            __hip_atomic_store(&cnt[gid * 16], 0u, __ATOMIC_RELAXED, __HIP_MEMORY_SCOPE_AGENT);
            unsigned r = __hip_atomic_fetch_add(root, 1u,
                                                __ATOMIC_ACQ_REL, __HIP_MEMORY_SCOPE_AGENT);
            if (r == NGRP - 1) {
                __hip_atomic_store(root, 0u, __ATOMIC_RELAXED, __HIP_MEMORY_SCOPE_AGENT);
                __hip_atomic_fetch_add(gen, 1u, __ATOMIC_RELEASE, __HIP_MEMORY_SCOPE_AGENT);
            } else {
                while (__hip_atomic_load(gen, __ATOMIC_ACQUIRE, __HIP_MEMORY_SCOPE_AGENT) == g)
                    __builtin_amdgcn_s_sleep(2);
            }
        } else {
            while (__hip_atomic_load(gen, __ATOMIC_ACQUIRE, __HIP_MEMORY_SCOPE_AGENT) == g)
                __builtin_amdgcn_s_sleep(2);
        }
        __threadfence();   // acquire side: subsequent gp reads see fresh data
    }
    __syncthreads();
}

// ---------------------------------------------------------------------------
// Phased persistent kernel — locality, not retention:
//   phase (8 whole batches, 67 MB window):
//     pass A: read 4 planes, means -> gp          (allocates L3)
//     grid barrier
//     pass B: RE-READ the same 4 planes (L3-hot), gate, scale, NT-store.
// No registers/LDS held across the barrier -> no spills (R6 lesson).
// HBM sees: input fetched once (134 MB) + output written once (134 MB);
// pass B's re-read is served by Infinity Cache.
// ---------------------------------------------------------------------------
__global__ __launch_bounds__(256, 4) void fused_kernel(
    const float* __restrict__ x1, const float* __restrict__ x2,
    const float* __restrict__ x3, const float* __restrict__ x4,
    const float* __restrict__ conv_w, const float* __restrict__ conv_b,
    const float* __restrict__ lin_w,  const float* __restrict__ lin_b,
    float* __restrict__ gp, unsigned* __restrict__ bar,
    float* __restrict__ out)
{
    const int tid = threadIdx.x;
    const int blk = blockIdx.x;
    const int gid = blk >> 6;              // 16 groups of 64 blocks
    unsigned* cnt  = bar;
    unsigned* root = bar + NGRP * 16;
    unsigned* gen  = bar + NGRP * 16 + 16;

    __shared__ float gwin[PPB + 64];       // gp[b, c1-32 .. c1+PPB+31]
    __shared__ float wsum[PPB][4];
    __shared__ float gates[PPB];

    for (int g = 0; g < NPHASE; ++g) {
        const int pA = g * (NBLK * PPB) + blk * PPB;   // first plane (mult of 4)
        const int b  = pA >> 9;
        const int c1 = pA & (CHANS - 1);
        const int xi = c1 >> 7;            // 4 | 128 -> all 4 planes same source
        const float* src = (xi == 0) ? x1 : (xi == 1) ? x2 : (xi == 2) ? x3 : x4;
        const f32x4* p4 = (const f32x4*)(src + (size_t)(b * 128 + (c1 & 127)) * PLANE_SZ);

        // ---- pass A: means (nothing retained) ----
        float s[PPB];
        #pragma unroll
        for (int p = 0; p < PPB; ++p) {
            f32x4 acc = p4[p * 1024 + tid];
            #pragma unroll
            for (int j = 1; j < 4; ++j)
                acc += p4[p * 1024 + j * 256 + tid];
            s[p] = (acc.x + acc.y) + (acc.z + acc.w);
        }
        #pragma unroll
        for (int off = 32; off > 0; off >>= 1)
            #pragma unroll
            for (int p = 0; p < PPB; ++p)
                s[p] += __shfl_down(s[p], off, 64);
        if ((tid & 63) == 0)
            #pragma unroll
            for (int p = 0; p < PPB; ++p)
                wsum[p][tid >> 6] = s[p];
        __syncthreads();
        if (tid < PPB)
            gp[pA + tid] = ((wsum[tid][0] + wsum[tid][1]) +
                            (wsum[tid][2] + wsum[tid][3])) * (1.0f / PLANE_SZ);

        grid_barrier(cnt, root, gen, gid);   // all means of this phase visible

        // ---- pass B: gates from gp window ----
        if (tid < PPB + 64) {
            int idx = c1 - 32 + tid;
            gwin[tid] = (idx >= 0 && idx < CHANS) ? gp[b * CHANS + idx] : 0.f;
        }
        __syncthreads();
        if (tid < PPB) {
            float lin = lin_b[0];
            #pragma unroll
            for (int i = 0; i < 4; ++i) {
                const int d = 1 << i;
                float acc = conv_b[i];
                #pragma unroll
                for (int k = 0; k < 9; ++k)
                    acc += conv_w[i * 9 + k] * gwin[32 + tid + d * (k - 4)];
                lin += lin_w[i] * fmaxf(acc, 0.f);
            }
            gates[tid] = 1.0f / (1.0f + expf(-lin));
        }
        __syncthreads();

        // ---- pass B: re-read (L3-hot), scale, NT-store ----
        f32x4* o4 = (f32x4*)(out + (size_t)pA * PLANE_SZ);
        #pragma unroll
        for (int p = 0; p < PPB; ++p) {
            const float gv = gates[p];
            #pragma unroll
            for (int j = 0; j < 4; ++j) {
                f32x4 t = p4[p * 1024 + j * 256 + tid] * gv;
                __builtin_nontemporal_store(t, &o4[p * 1024 + j * 256 + tid]);
            }
        }
        __syncthreads();   // gwin/wsum safe before next phase overwrite
    }
}

extern "C" void kernel_launch(void* const* d_in, const int* in_sizes, int n_in,
                              void* d_out, int out_size, void* d_ws, size_t ws_size,
                              hipStream_t stream) {
    const float* x1     = (const float*)d_in[0];
    const float* x2     = (const float*)d_in[1];
    const float* x3     = (const float*)d_in[2];
    const float* x4     = (const float*)d_in[3];
    const float* conv_w = (const float*)d_in[4];
    const float* conv_b = (const float*)d_in[5];
    const float* lin_w  = (const float*)d_in[6];
    const float* lin_b  = (const float*)d_in[7];
    float* out = (float*)d_out;

    float*    gp  = (float*)d_ws;                         // PLANES floats
    unsigned* bar = (unsigned*)((char*)d_ws + PLANES * sizeof(float));

    // barrier state must be zero at the start of EVERY call (ws is poisoned)
    hipMemsetAsync(bar, 0, 4096, stream);

    fused_kernel<<<NBLK, 256, 0, stream>>>(x1, x2, x3, x4,
                                           conv_w, conv_b, lin_w, lin_b,
                                           gp, bar, out);
}

// Round 8
// 67.970 us; speedup vs baseline: 5.2738x; 5.2738x over previous
//
#include <hip/hip_runtime.h>
#include <math.h>

#define PLANES   8192   // 16 batches * 512 channels
#define PLANE_SZ 4096   // 64*64
#define CHANS    512

typedef float f32x4 __attribute__((ext_vector_type(4)));

// ---------------------------------------------------------------------------
// Kernel 1: gp[b,c] = mean over the 64x64 plane of map1[b,c]
// One block per (b,c) plane. Normal (allocating) loads -> input lands in L3.
// ---------------------------------------------------------------------------
__global__ __launch_bounds__(256) void gp_reduce_kernel(
    const float* __restrict__ x1, const float* __restrict__ x2,
    const float* __restrict__ x3, const float* __restrict__ x4,
    float* __restrict__ gp)
{
    const int plane = blockIdx.x;          // b*512 + c
    const int c = plane & (CHANS - 1);
    const int b = plane >> 9;
    const int xi = c >> 7;                 // which of x1..x4
    const float* src = (xi == 0) ? x1 : (xi == 1) ? x2 : (xi == 2) ? x3 : x4;
    src += (size_t)(b * 128 + (c & 127)) * PLANE_SZ;

    const int tid = threadIdx.x;
    const f32x4* p4 = (const f32x4*)src;
    float s = 0.f;
    #pragma unroll
    for (int j = 0; j < 4; ++j) {
        f32x4 v = p4[tid + j * 256];
        s += (v.x + v.y) + (v.z + v.w);
    }
    #pragma unroll
    for (int off = 32; off > 0; off >>= 1)
        s += __shfl_down(s, off, 64);

    __shared__ float wsum[4];
    const int lane = tid & 63, wv = tid >> 6;
    if (lane == 0) wsum[wv] = s;
    __syncthreads();
    if (tid == 0) {
        float t = (wsum[0] + wsum[1]) + (wsum[2] + wsum[3]);
        gp[plane] = t * (1.0f / PLANE_SZ);
    }
}

// ---------------------------------------------------------------------------
// Kernel 2 (fused gate + scale), L3-aware ordering:
//  - planes processed in REVERSE of k1's read order: the most-recently-read
//    (L3-MRU) planes are consumed first, while the output stream's evictions
//    consume the LRU end -> maximizes Infinity-Cache hits on the re-read
//  - re-read uses NON-TEMPORAL loads: hits still hit, misses don't
//    re-allocate (no self-thrash)
//  - output uses non-temporal stores
// ---------------------------------------------------------------------------
__global__ __launch_bounds__(256) void gate_scale_kernel(
    const float* __restrict__ x1, const float* __restrict__ x2,
    const float* __restrict__ x3, const float* __restrict__ x4,
    const float* __restrict__ gp,
    const float* __restrict__ conv_w, const float* __restrict__ conv_b,
    const float* __restrict__ lin_w,  const float* __restrict__ lin_b,
    float* __restrict__ out)
{
    const int plane = (PLANES - 1) - blockIdx.x;   // reverse order
    const int c = plane & (CHANS - 1);
    const int b = plane >> 9;
    const int xi = c >> 7;
    const float* src = (xi == 0) ? x1 : (xi == 1) ? x2 : (xi == 2) ? x3 : x4;
    src += (size_t)(b * 128 + (c & 127)) * PLANE_SZ;

    const int tid = threadIdx.x;
    const f32x4* p4 = (const f32x4*)src;

    // issue plane re-loads early (non-temporal: don't re-allocate on miss)
    f32x4 v0 = __builtin_nontemporal_load(&p4[tid]);
    f32x4 v1 = __builtin_nontemporal_load(&p4[tid + 256]);
    f32x4 v2 = __builtin_nontemporal_load(&p4[tid + 512]);
    f32x4 v3 = __builtin_nontemporal_load(&p4[tid + 768]);

    // gate (wave-uniform; taps at c + d*(k-4), d = 1,2,4,8)
    const float* g = gp + b * CHANS;
    float lin = lin_b[0];
    #pragma unroll
    for (int i = 0; i < 4; ++i) {
        const int d = 1 << i;
        float acc = conv_b[i];
        #pragma unroll
        for (int k = 0; k < 9; ++k) {
            const int t = c + d * (k - 4);
            if (t >= 0 && t < CHANS) acc += conv_w[i * 9 + k] * g[t];
        }
        lin += lin_w[i] * fmaxf(acc, 0.f);
    }
    const float gv = 1.0f / (1.0f + expf(-lin));

    f32x4* o4 = (f32x4*)(out + (size_t)plane * PLANE_SZ);
    v0 *= gv; v1 *= gv; v2 *= gv; v3 *= gv;
    __builtin_nontemporal_store(v0, &o4[tid]);
    __builtin_nontemporal_store(v1, &o4[tid + 256]);
    __builtin_nontemporal_store(v2, &o4[tid + 512]);
    __builtin_nontemporal_store(v3, &o4[tid + 768]);
}

extern "C" void kernel_launch(void* const* d_in, const int* in_sizes, int n_in,
                              void* d_out, int out_size, void* d_ws, size_t ws_size,
                              hipStream_t stream) {
    const float* x1     = (const float*)d_in[0];
    const float* x2     = (const float*)d_in[1];
    const float* x3     = (const float*)d_in[2];
    const float* x4     = (const float*)d_in[3];
    const float* conv_w = (const float*)d_in[4];
    const float* conv_b = (const float*)d_in[5];
    const float* lin_w  = (const float*)d_in[6];
    const float* lin_b  = (const float*)d_in[7];
    float* out = (float*)d_out;

    float* gp = (float*)d_ws;              // PLANES floats

    gp_reduce_kernel<<<PLANES, 256, 0, stream>>>(x1, x2, x3, x4, gp);
    gate_scale_kernel<<<PLANES, 256, 0, stream>>>(x1, x2, x3, x4, gp,
                                                  conv_w, conv_b, lin_w, lin_b, out);
}